// Round 8
// baseline (6928.468 us; speedup 1.0000x reference)
//
#include <hip/hip_runtime.h>
#include <cstddef>
#include <cstdint>

#define LAT 512
#define HID 1024
#define NSLOT 16
#define NB 256
#define HOR 64

using short8  = __attribute__((ext_vector_type(8))) short;
using floatx4 = __attribute__((ext_vector_type(4))) float;

__device__ __forceinline__ float sigmoid_f(float x) { return 1.0f / (1.0f + __expf(-x)); }
__device__ __forceinline__ float tanh_f(float x) {
    float e = __expf(2.0f * x);
    return 1.0f - 2.0f / (e + 1.0f);
}
__device__ __forceinline__ unsigned short f2bf(float f) {
    union { float f; uint32_t u; } v; v.f = f;
    uint32_t u = v.u;
    return (unsigned short)((u + 0x7fffu + ((u >> 16) & 1u)) >> 16);
}
// async global->LDS, 16B per lane. LDS dest is wave-uniform base + lane*16.
__device__ __forceinline__ void async16(const void* g, void* l) {
    __builtin_amdgcn_global_load_lds(
        (const __attribute__((address_space(1))) unsigned int*)(unsigned long long)g,
        (__attribute__((address_space(3))) unsigned int*)(unsigned int)(unsigned long long)l,
        16, 0, 0);
}

// ---------------------------------------------------------------------------
// ROUND-7-VERIFIED GEMM BODY as a device function (byte-preserved logic).
// 512 threads = TWO K-TEAMS of 4 waves (2x2), team tk covers K range
// [tk*K/2,(tk+1)*K/2). Drain-style double buffer: stage(it+1) issued before
// compute(it); trailing __syncthreads (vmcnt(0)+lgkmcnt(0)+s_barrier) drains.
// Swizzle: chunk c of row m at in-row slot c^(m&7); reads at (s*4+q)^(m&7).
// Cross-team reduction via team-1's dead B region; team 0 runs the epilogue.
// MODE 1: +bias, ReLU, bf16 -> Cb.   MODE 2: +bias, fp32 -> Cf AND bf16 -> Cb.
// MODE 3 (BN=128): fused LSTM pointwise (gate-interleaved packed W): thread
//   fragment j = gate j (i,f,g,o) of feature jj; c (fp32, Cf) RMW by owner.
// ---------------------------------------------------------------------------
template<int BM, int BN, int MODE>
__device__ __forceinline__ void gemm_phase(
    const unsigned short* __restrict__ A, int lda,
    const unsigned short* __restrict__ W, int ldw, int K,
    const float* __restrict__ bias,
    float* __restrict__ Cf, int ldc,
    unsigned short* __restrict__ Cb, int ldcb,
    unsigned short* __restrict__ Cb2, int ldcb2,
    int m0, int n0, short* AsL, short* BsL, int t)
{
    constexpr int WM = BM / 2, WN = BN / 2, TM = WM / 16, TN = WN / 16;
    static_assert(MODE != 3 || TN == 4, "MODE 3 needs BN=128");
    const int tk   = t >> 8;          // K-team 0/1
    const int lt   = t & 255;
    const int lane = lt & 63;
    const int w    = lt >> 6;
    const int wm   = w >> 1, wn = w & 1;
    const int kb   = tk * (K / 2);

    const int r8 = lane >> 3;
    const int cx = (lane & 7) ^ r8;
    const int q  = lane >> 4;
    const int ml = lane & 15;

    short* Ast = AsL + tk * (2 * BM * 64);   // team LDS regions
    short* Bst = BsL + tk * (2 * BN * 64);

    floatx4 acc[TM][TN];
    const floatx4 zf = {0.f, 0.f, 0.f, 0.f};
    #pragma unroll
    for (int i = 0; i < TM; ++i)
        #pragma unroll
        for (int j = 0; j < TN; ++j) acc[i][j] = zf;

    auto stage = [&](int k0, int buf) {
        short* ad = Ast + buf * (BM * 64);
        short* bd = Bst + buf * (BN * 64);
        #pragma unroll
        for (int u = 0; u < BM / 32; ++u) {
            const int row = w * (BM / 4) + u * 8;
            async16(A + (size_t)(m0 + row + r8) * lda + k0 + cx * 8, ad + row * 64);
        }
        #pragma unroll
        for (int u = 0; u < BN / 32; ++u) {
            const int row = w * (BN / 4) + u * 8;
            async16(W + (size_t)(n0 + row + r8) * ldw + k0 + cx * 8, bd + row * 64);
        }
    };

    stage(kb, 0);
    __syncthreads();                                     // drains vmcnt -> buf0 ready
    const int nk = (K / 2) / 64;
    for (int it = 0; it < nk; ++it) {
        if (it + 1 < nk) stage(kb + (it + 1) * 64, (it + 1) & 1);   // prefetch next
        const short* as = Ast + (it & 1) * (BM * 64);
        const short* bs = Bst + (it & 1) * (BN * 64);
        #pragma unroll
        for (int s = 0; s < 2; ++s) {
            short8 af[TM], bfr[TN];
            #pragma unroll
            for (int i = 0; i < TM; ++i) {
                const int m = wm * WM + i * 16 + ml;
                af[i] = *(const short8*)&as[(m * 8 + ((s * 4 + q) ^ (m & 7))) * 8];
            }
            #pragma unroll
            for (int j = 0; j < TN; ++j) {
                const int n = wn * WN + j * 16 + ml;
                bfr[j] = *(const short8*)&bs[(n * 8 + ((s * 4 + q) ^ (n & 7))) * 8];
            }
            #pragma unroll
            for (int i = 0; i < TM; ++i)
                #pragma unroll
                for (int j = 0; j < TN; ++j)
                    acc[i][j] = __builtin_amdgcn_mfma_f32_16x16x32_bf16(af[i], bfr[j], acc[i][j], 0, 0, 0);
        }
        __syncthreads();                                 // drain prefetch + protect bufs
    }

    // cross-team reduction in team-1's (dead) B region, thread-flat.
    floatx4* ex = (floatx4*)(BsL + 2 * BN * 64);
    if (tk == 1) {
        #pragma unroll
        for (int i = 0; i < TM; ++i)
            #pragma unroll
            for (int j = 0; j < TN; ++j)
                ex[lt * (TM * TN) + i * TN + j] = acc[i][j];
    }
    __syncthreads();
    if (tk == 0) {
        #pragma unroll
        for (int i = 0; i < TM; ++i)
            #pragma unroll
            for (int j = 0; j < TN; ++j) {
                const floatx4 o = ex[lt * (TM * TN) + i * TN + j];
                acc[i][j][0] += o[0]; acc[i][j][1] += o[1];
                acc[i][j][2] += o[2]; acc[i][j][3] += o[3];
            }

        // epilogue (team 0 only): C/D layout col = lane&15, row = q*4 + reg
        const int gmb = m0 + wm * WM + q * 4;
        if constexpr (MODE == 3) {
            const int nn = n0 + wn * WN;
            const int jj = (nn >> 6) * 16 + ml;
            const float bI = bias[nn + ml],      bF = bias[nn + 16 + ml];
            const float bG = bias[nn + 32 + ml], bO = bias[nn + 48 + ml];
            #pragma unroll
            for (int i = 0; i < TM; ++i)
                #pragma unroll
                for (int r = 0; r < 4; ++r) {
                    const int b = gmb + i * 16 + r;
                    const float i_ = sigmoid_f(acc[i][0][r] + bI);
                    const float f_ = sigmoid_f(acc[i][1][r] + bF);
                    const float g_ = tanh_f(acc[i][2][r] + bG);
                    const float o_ = sigmoid_f(acc[i][3][r] + bO);
                    float* cp = Cf + (size_t)b * ldc + jj;   // unique owner
                    const float cn = f_ * (*cp) + i_ * g_;
                    *cp = cn;
                    const unsigned short hb = f2bf(o_ * tanh_f(cn));
                    Cb[(size_t)b * ldcb + jj] = hb;
                    if (Cb2) Cb2[(size_t)b * ldcb2 + jj] = hb;
                }
        } else {
            const int gnb = n0 + wn * WN + ml;
            #pragma unroll
            for (int i = 0; i < TM; ++i)
                #pragma unroll
                for (int j = 0; j < TN; ++j) {
                    const int gm = gmb + i * 16, gn = gnb + j * 16;
                    const float bv = bias[gn];
                    #pragma unroll
                    for (int r = 0; r < 4; ++r) {
                        float v = acc[i][j][r] + bv;
                        if (MODE == 1) v = fmaxf(v, 0.f);
                        if (MODE == 2) Cf[(size_t)(gm + r) * ldc + gn] = v;
                        Cb[(size_t)(gm + r) * ldcb + gn] = f2bf(v);
                    }
                }
        }
    }
    __syncthreads();                                     // ex consumed; LDS free
}

// ---------------------------------------------------------------------------
// Grid barrier — ROUND-1-VERIFIED pattern; only arrival count adapted for
// 128 blocks (8 splits x 16 arrivals; gen target round*8 unchanged).
// ---------------------------------------------------------------------------
__device__ __forceinline__ void gridbar(unsigned* bar, int round)
{
    __syncthreads();
    if (threadIdx.x == 0) {
        __threadfence();
        unsigned old = atomicAdd(&bar[(blockIdx.x & 7) << 6], 1u);
        if (old == (unsigned)round * 16u - 1u)           // last of this split's 16
            atomicAdd(&bar[512], 1u);
        while (__hip_atomic_load(&bar[512], __ATOMIC_RELAXED, __HIP_MEMORY_SCOPE_AGENT)
               < (unsigned)round * 8u)
            __builtin_amdgcn_s_sleep(2);
        __threadfence();
    }
    __syncthreads();
}

struct RollArgs {
    const unsigned short* Wg0;   // [4096][1536] gate-interleaved packed
    const unsigned short* Wg1;   // [4096][2048]
    const unsigned short* Wo1;   // [1024][1024]
    const unsigned short* Wo2;   // [512][1024]
    const float* bc0;            // [4096] combined packed bias
    const float* bc1;            // [4096]
    const float* ob1;            // [1024]
    const float* ob2;            // [512]
    unsigned short* xh0;         // 2 x [NB][LAT+HID] ping-pong
    unsigned short* hh1;         // 2 x [NB][2*HID]   ping-pong
    float* c0;                   // [NB][HID]
    float* c1;                   // [NB][HID]
    unsigned short* tbuf;        // [NB][HID]
    float* out;                  // [NB][HOR][LAT]
    unsigned* bar;
};

// ---------------------------------------------------------------------------
// Persistent rollout: round-7's dispatch sequence with dispatch boundaries
// replaced by gridbar. 128 blocks x 512 threads; block = (n-tile, m-tile) =
// (blk>>2, blk&3). Gates use all 128 blocks; op1 blocks<64; op2 blocks<32
// (idle blocks just barrier). LDS 96 KB (gates shapes; op shapes subrange).
// ---------------------------------------------------------------------------
__global__ __launch_bounds__(512)
void rollout(RollArgs a)
{
    __shared__ __attribute__((aligned(16))) short AsL[2 * 2 * 64 * 64];    // 32 KB
    __shared__ __attribute__((aligned(16))) short BsL[2 * 2 * 128 * 64];   // 64 KB

    const int t   = threadIdx.x;
    const int blk = blockIdx.x;
    const int nb  = blk >> 2;        // n-tile
    const int mb  = blk & 3;         // m-tile (64 rows)
    int round = 0;

    for (int step = 0; step < HOR; ++step) {
        const int cur = step & 1, nxt = cur ^ 1;
        unsigned short* xh_r = a.xh0 + (size_t)cur * NB * (LAT + HID);
        unsigned short* xh_w = a.xh0 + (size_t)nxt * NB * (LAT + HID);
        unsigned short* hh_c = a.hh1 + (size_t)cur * NB * (2 * HID);
        unsigned short* hh_n = a.hh1 + (size_t)nxt * NB * (2 * HID);

        // P1: gates0 + pw: h0 -> hh_c[:, :HID] AND xh_w[:, LAT:]
        gemm_phase<64, 128, 3>(
            xh_r, LAT + HID, a.Wg0, LAT + HID, LAT + HID,
            a.bc0, a.c0, HID, hh_c, 2 * HID, xh_w + LAT, LAT + HID,
            mb * 64, nb * 128, AsL, BsL, t);
        gridbar(a.bar, ++round);

        // P2: gates1 + pw: h1 -> hh_n[:, HID:]
        gemm_phase<64, 128, 3>(
            hh_c, 2 * HID, a.Wg1, 2 * HID, 2 * HID,
            a.bc1, a.c1, HID, hh_n + HID, 2 * HID, nullptr, 0,
            mb * 64, nb * 128, AsL, BsL, t);
        gridbar(a.bar, ++round);

        // P3: t = relu(h1 @ Wo1^T + b1) -> tbuf (blocks 0..63)
        if (blk < 64)
            gemm_phase<64, 64, 1>(
                hh_n + HID, 2 * HID, a.Wo1, HID, HID,
                a.ob1, nullptr, 0, a.tbuf, HID, nullptr, 0,
                mb * 64, nb * 64, AsL, BsL, t);
        gridbar(a.bar, ++round);

        // P4: pred = t @ Wo2^T + b2 -> out[:,step,:] AND xh_w[:, :LAT] (blocks 0..31)
        if (blk < 32)
            gemm_phase<64, 64, 2>(
                a.tbuf, HID, a.Wo2, HID, HID,
                a.ob2, a.out + (size_t)step * LAT, HOR * LAT, xh_w, LAT + HID, nullptr, 0,
                mb * 64, nb * 64, AsL, BsL, t);
        gridbar(a.bar, ++round);
    }
}

// ---------------------------------------------------------------------------
// Weight packing (verified)
// ---------------------------------------------------------------------------
__global__ __launch_bounds__(256)
void pack_gates(const float* __restrict__ w_ih, int Kih,
                const float* __restrict__ w_hh, int Khh,
                const float* __restrict__ b_ih, const float* __restrict__ b_hh,
                unsigned short* __restrict__ d, float* __restrict__ bc, int K)
{
    const int idx = blockIdx.x * 256 + threadIdx.x;
    if (idx >= 4096 * K) return;
    const int p = idx / K;
    const int k = idx - p * K;
    const int g = (p >> 4) & 3;
    const int j = ((p >> 6) << 4) | (p & 15);
    const int orow = g * 1024 + j;
    const float v = (k < Kih) ? w_ih[(size_t)orow * Kih + k]
                              : w_hh[(size_t)orow * Khh + (k - Kih)];
    d[idx] = f2bf(v);
    if (k == 0) bc[p] = b_ih[orow] + b_hh[orow];
}

__global__ __launch_bounds__(256)
void pack2(const float* __restrict__ s1, int K1, const float* __restrict__ s2, int K2,
           unsigned short* __restrict__ d, int total, int K)
{
    const int idx = blockIdx.x * 256 + threadIdx.x;
    if (idx >= total) return;
    const int n = idx / K;
    const int k = idx - n * K;
    const float v = (k < K1) ? s1[(size_t)n * K1 + k] : s2[(size_t)n * K2 + (k - K1)];
    d[idx] = f2bf(v);
}

// ---------------------------------------------------------------------------
// fp32 prologue GEMM (attention + prior): small, runs once. C2 = bf16 copy.
// ---------------------------------------------------------------------------
template<int RELU>
__global__ __launch_bounds__(256)
void gemm_tn(const float* __restrict__ A1, int lda1,
             const float* __restrict__ W1, int ldw1, int K1,
             const float* __restrict__ A2, int lda2,
             const float* __restrict__ W2, int ldw2, int K2,
             const float* __restrict__ bias1,
             float* __restrict__ C, int ldc,
             unsigned short* __restrict__ C2, int ldc2,
             int M, int N)
{
    __shared__ float As[16][64];
    __shared__ float Ws[16][64];
    const int t   = threadIdx.x;
    const int bn0 = blockIdx.x * 64;
    const int bm0 = blockIdx.y * 64;
    const int tx  = t & 15;
    const int ty  = t >> 4;
    const int lr  = t >> 2;
    const int lc  = (t & 3) << 2;

    float acc[4][4] = {};

    for (int src = 0; src < 2; ++src) {
        const float* A = src ? A2 : A1;
        if (!A) continue;
        const float* W = src ? W2 : W1;
        const int lda = src ? lda2 : lda1;
        const int ldw = src ? ldw2 : ldw1;
        const int K   = src ? K2 : K1;
        for (int k0 = 0; k0 < K; k0 += 16) {
            float4 av = make_float4(0.f, 0.f, 0.f, 0.f);
            const int am = bm0 + lr;
            if (am < M) av = *(const float4*)(A + (size_t)am * lda + k0 + lc);
            const float4 wv = *(const float4*)(W + (size_t)(bn0 + lr) * ldw + k0 + lc);
            __syncthreads();
            As[lc + 0][lr] = av.x; As[lc + 1][lr] = av.y;
            As[lc + 2][lr] = av.z; As[lc + 3][lr] = av.w;
            Ws[lc + 0][lr] = wv.x; Ws[lc + 1][lr] = wv.y;
            Ws[lc + 2][lr] = wv.z; Ws[lc + 3][lr] = wv.w;
            __syncthreads();
            #pragma unroll
            for (int kk = 0; kk < 16; ++kk) {
                const float4 a = *(const float4*)&As[kk][ty * 4];
                const float4 b = *(const float4*)&Ws[kk][tx * 4];
                const float ar[4] = {a.x, a.y, a.z, a.w};
                const float br[4] = {b.x, b.y, b.z, b.w};
                #pragma unroll
                for (int i = 0; i < 4; ++i)
                    #pragma unroll
                    for (int j = 0; j < 4; ++j)
                        acc[i][j] = fmaf(ar[i], br[j], acc[i][j]);
            }
        }
    }

    const int n0 = bn0 + tx * 4;
    float bv[4] = {0.f, 0.f, 0.f, 0.f};
    if (bias1) {
        #pragma unroll
        for (int j = 0; j < 4; ++j) bv[j] += bias1[n0 + j];
    }
    #pragma unroll
    for (int i = 0; i < 4; ++i) {
        const int m = bm0 + ty * 4 + i;
        if (m < M) {
            float ov[4];
            #pragma unroll
            for (int j = 0; j < 4; ++j) {
                float v = acc[i][j] + bv[j];
                if (RELU) v = fmaxf(v, 0.f);
                ov[j] = v;
            }
            *(float4*)(C + (size_t)m * ldc + n0) = make_float4(ov[0], ov[1], ov[2], ov[3]);
            if (C2) {
                #pragma unroll
                for (int j = 0; j < 4; ++j)
                    C2[(size_t)m * ldc2 + n0 + j] = f2bf(ov[j]);
            }
        }
    }
}

__global__ __launch_bounds__(256)
void attn_kernel(const float* __restrict__ q, const float* __restrict__ k,
                 const float* __restrict__ v, float* __restrict__ ctx)
{
    __shared__ float red[NSLOT][4];
    __shared__ float wts[NSLOT];
    const int b = blockIdx.x;
    const int t = threadIdx.x;
    const float4 qv = *(const float4*)(q + (size_t)b * HID + t * 4);
    #pragma unroll
    for (int s = 0; s < NSLOT; ++s) {
        const float4 kv = *(const float4*)(k + (size_t)s * HID + t * 4);
        float p = qv.x * kv.x + qv.y * kv.y + qv.z * kv.z + qv.w * kv.w;
        #pragma unroll
        for (int off = 32; off > 0; off >>= 1) p += __shfl_down(p, off);
        if ((t & 63) == 0) red[s][t >> 6] = p;
    }
    __syncthreads();
    if (t == 0) {
        float sc[NSLOT];
        float mx = -1e30f;
        for (int s = 0; s < NSLOT; ++s) {
            sc[s] = (red[s][0] + red[s][1] + red[s][2] + red[s][3]) * 0.03125f;
            mx = fmaxf(mx, sc[s]);
        }
        float sum = 0.f;
        for (int s = 0; s < NSLOT; ++s) { const float e = __expf(sc[s] - mx); wts[s] = e; sum += e; }
        const float inv = 1.f / sum;
        for (int s = 0; s < NSLOT; ++s) wts[s] *= inv;
    }
    __syncthreads();
    float4 a = make_float4(0.f, 0.f, 0.f, 0.f);
    #pragma unroll
    for (int s = 0; s < NSLOT; ++s) {
        const float wv = wts[s];
        const float4 vv = *(const float4*)(v + (size_t)s * HID + t * 4);
        a.x += wv * vv.x; a.y += wv * vv.y; a.z += wv * vv.z; a.w += wv * vv.w;
    }
    *(float4*)(ctx + (size_t)b * HID + t * 4) = a;
}

extern "C" void kernel_launch(void* const* d_in, const int* in_sizes, int n_in,
                              void* d_out, int out_size, void* d_ws, size_t ws_size,
                              hipStream_t stream)
{
    const float* cs    = (const float*)d_in[0];
    const float* mem   = (const float*)d_in[2];
    const float* q_W   = (const float*)d_in[3];
    const float* q_b   = (const float*)d_in[4];
    const float* k_W   = (const float*)d_in[5];
    const float* k_b   = (const float*)d_in[6];
    const float* v_W   = (const float*)d_in[7];
    const float* v_b   = (const float*)d_in[8];
    const float* mo_W  = (const float*)d_in[9];
    const float* mo_b  = (const float*)d_in[10];
    const float* pg_W1 = (const float*)d_in[11];
    const float* pg_b1 = (const float*)d_in[12];
    const float* pg_W2 = (const float*)d_in[13];
    const float* pg_b2 = (const float*)d_in[14];
    const float* w_ih0 = (const float*)d_in[15];
    const float* w_hh0 = (const float*)d_in[16];
    const float* b_ih0 = (const float*)d_in[17];
    const float* b_hh0 = (const float*)d_in[18];
    const float* w_ih1 = (const float*)d_in[19];
    const float* w_hh1 = (const float*)d_in[20];
    const float* b_ih1 = (const float*)d_in[21];
    const float* b_hh1 = (const float*)d_in[22];
    const float* op_W1 = (const float*)d_in[23];
    const float* op_b1 = (const float*)d_in[24];
    const float* op_W2 = (const float*)d_in[25];
    const float* op_b2 = (const float*)d_in[26];

    float* out       = (float*)d_out;
    float* prior_out = out + (size_t)NB * HOR * LAT;

    char* base = (char*)d_ws;
    auto alloc = [&](size_t bytes) { char* r = base; base += (bytes + 255) & ~255ull; return r; };

    unsigned short* Wg0p = (unsigned short*)alloc((size_t)4 * HID * (LAT + HID) * 2);
    unsigned short* Wg1p = (unsigned short*)alloc((size_t)4 * HID * (2 * HID) * 2);
    unsigned short* Wo1  = (unsigned short*)alloc((size_t)HID * HID * 2);
    unsigned short* Wo2  = (unsigned short*)alloc((size_t)LAT * HID * 2);
    float*          bc0  = (float*)alloc((size_t)4 * HID * 4);
    float*          bc1  = (float*)alloc((size_t)4 * HID * 4);
    // zero-init region (contiguous, 256B-multiple sizes): xh0[2], hh1[2], c0, c1, bar
    unsigned short* xh0  = (unsigned short*)alloc((size_t)2 * NB * (LAT + HID) * 2);
    unsigned short* hh1  = (unsigned short*)alloc((size_t)2 * NB * (2 * HID) * 2);
    float*          c0   = (float*)alloc((size_t)NB * HID * 4);
    float*          c1   = (float*)alloc((size_t)NB * HID * 4);
    unsigned*       bar  = (unsigned*)alloc(4096);
    unsigned short* tbuf = (unsigned short*)alloc((size_t)NB * HID * 2);
    float* qbuf   = (float*)alloc((size_t)NB * HID * 4);
    float* kbuf   = (float*)alloc((size_t)NSLOT * HID * 4);
    float* vbuf   = (float*)alloc((size_t)NSLOT * HID * 4);
    float* ctxbuf = (float*)alloc((size_t)NB * HID * 4);
    float* ctxo   = (float*)alloc((size_t)NB * LAT * 4);
    float* pgh    = (float*)alloc((size_t)NB * HID * 4);

    const size_t zbytes = (size_t)2 * NB * (LAT + HID) * 2
                        + (size_t)2 * NB * (2 * HID) * 2
                        + (size_t)NB * HID * 4 * 2 + 4096;
    hipMemsetAsync(xh0, 0, zbytes, stream);

    const dim3 blk(256);

    // ---- pack weights (gates: gate-interleaved + combined bias) ----
    {
        int tot = 4 * HID * (LAT + HID);
        pack_gates<<<dim3((tot + 255) / 256), blk, 0, stream>>>(
            w_ih0, LAT, w_hh0, HID, b_ih0, b_hh0, Wg0p, bc0, LAT + HID);
        tot = 4 * HID * (2 * HID);
        pack_gates<<<dim3((tot + 255) / 256), blk, 0, stream>>>(
            w_ih1, HID, w_hh1, HID, b_ih1, b_hh1, Wg1p, bc1, 2 * HID);
        tot = HID * HID;
        pack2<<<dim3((tot + 255) / 256), blk, 0, stream>>>(op_W1, HID, nullptr, 0, Wo1, tot, HID);
        tot = LAT * HID;
        pack2<<<dim3((tot + 255) / 256), blk, 0, stream>>>(op_W2, HID, nullptr, 0, Wo2, tot, HID);
    }

    // ---- prologue (fp32): attention read + prior ----
    gemm_tn<0><<<dim3(HID / 64, 1), blk, 0, stream>>>(
        mem, HID, k_W, HID, HID, nullptr, 0, nullptr, 0, 0,
        k_b, kbuf, HID, nullptr, 0, NSLOT, HID);
    gemm_tn<0><<<dim3(HID / 64, 1), blk, 0, stream>>>(
        mem, HID, v_W, HID, HID, nullptr, 0, nullptr, 0, 0,
        v_b, vbuf, HID, nullptr, 0, NSLOT, HID);
    gemm_tn<0><<<dim3(HID / 64, NB / 64), blk, 0, stream>>>(
        cs, LAT, q_W, LAT, LAT, nullptr, 0, nullptr, 0, 0,
        q_b, qbuf, HID, nullptr, 0, NB, HID);
    attn_kernel<<<dim3(NB), blk, 0, stream>>>(qbuf, kbuf, vbuf, ctxbuf);
    gemm_tn<0><<<dim3(LAT / 64, NB / 64), blk, 0, stream>>>(
        ctxbuf, HID, mo_W, HID, HID, nullptr, 0, nullptr, 0, 0,
        mo_b, ctxo, LAT, nullptr, 0, NB, LAT);
    gemm_tn<1><<<dim3(HID / 64, NB / 64), blk, 0, stream>>>(
        cs, LAT, pg_W1, HID, LAT, ctxo, LAT, pg_W1 + LAT, HID, LAT,
        pg_b1, pgh, HID, nullptr, 0, NB, HID);
    // prior -> fp32 output AND bf16 x0 into xh0 buffer 0 (first 512 cols)
    gemm_tn<0><<<dim3(LAT / 64, NB / 64), blk, 0, stream>>>(
        pgh, HID, pg_W2, HID, HID, nullptr, 0, nullptr, 0, 0,
        pg_b2, prior_out, LAT, xh0, LAT + HID, NB, LAT);

    // ---- persistent cooperative LSTM rollout (r7 phases + r1 barrier) ----
    RollArgs ra;
    ra.Wg0 = Wg0p; ra.Wg1 = Wg1p; ra.Wo1 = Wo1; ra.Wo2 = Wo2;
    ra.bc0 = bc0;  ra.bc1 = bc1;  ra.ob1 = op_b1; ra.ob2 = op_b2;
    ra.xh0 = xh0;  ra.hh1 = hh1;  ra.c0 = c0; ra.c1 = c1;
    ra.tbuf = tbuf; ra.out = out; ra.bar = bar;
    void* kargs[] = { (void*)&ra };
    hipLaunchCooperativeKernel((const void*)rollout, dim3(128), dim3(512), kargs, 0, stream);
}

// Round 9
// 3077.944 us; speedup vs baseline: 2.2510x; 2.2510x over previous
//
#include <hip/hip_runtime.h>
#include <cstddef>
#include <cstdint>

#define LAT 512
#define HID 1024
#define NSLOT 16
#define NB 256
#define HOR 64

using short8  = __attribute__((ext_vector_type(8))) short;
using floatx4 = __attribute__((ext_vector_type(4))) float;

__device__ __forceinline__ float sigmoid_f(float x) { return 1.0f / (1.0f + __expf(-x)); }
__device__ __forceinline__ float tanh_f(float x) {
    float e = __expf(2.0f * x);
    return 1.0f - 2.0f / (e + 1.0f);
}
__device__ __forceinline__ unsigned short f2bf(float f) {
    union { float f; uint32_t u; } v; v.f = f;
    uint32_t u = v.u;
    return (unsigned short)((u + 0x7fffu + ((u >> 16) & 1u)) >> 16);
}
// async global->LDS, 16B per lane. LDS dest is wave-uniform base + lane*16.
__device__ __forceinline__ void async16(const void* g, void* l) {
    __builtin_amdgcn_global_load_lds(
        (const __attribute__((address_space(1))) unsigned int*)(unsigned long long)g,
        (__attribute__((address_space(3))) unsigned int*)(unsigned int)(unsigned long long)l,
        16, 0, 0);
}

// ---------------------------------------------------------------------------
// bf16 MFMA GEMM, one dispatch per op; TEAMS K-teams of 4 waves (2x2), team
// tk covers K range [tk*K/TEAMS, (tk+1)*K/TEAMS). Body = the r6/r7-VERIFIED
// drain-style code, generic in BM/TEAMS:
//   BM=64: WM=32, TM=2 (wave tile 32 x WN).  BM=32: WM=16, TM=1.
// Drain-style double buffer: stage(it+1) issued before compute(it); trailing
// __syncthreads (vmcnt(0)+lgkmcnt(0)+s_barrier) drains. NO counted vmcnt.
// Swizzle: chunk c of row m at in-row slot c^(m&7); reads at (s*4+q)^(m&7).
// Cross-team reduction: teams >=1 write acc thread-flat into their OWN dead
// B region (r8-verified trick, generalized); one sync; team 0 sums + epilogue.
// Sync counts are identical across teams (same nk).
// MODE 1: +bias, ReLU, bf16 -> Cb.   MODE 2: +bias, fp32 -> Cf AND bf16 -> Cb.
// MODE 3 (BN=128): fused LSTM pointwise (gate-interleaved packed W): thread
//   fragment j = gate j (i,f,g,o) of feature jj; c (fp32, Cf) RMW by owner.
// LDS: TEAMS*2*(BM+BN)*64 shorts. gates<32,128,3,4> = 160 KB (gfx950 max,
// allocatable: AITER fmha_v3 uses 160KB workgroups). ops<64,64,*,4> = 128 KB.
// ---------------------------------------------------------------------------
template<int BM, int BN, int MODE, int TEAMS>
__global__ __launch_bounds__(TEAMS * 256)
void mfma_gemm(const unsigned short* __restrict__ A, int lda,
               const unsigned short* __restrict__ W, int ldw, int K,
               const float* __restrict__ bias,
               float* __restrict__ Cf, int ldc,
               unsigned short* __restrict__ Cb, int ldcb,
               unsigned short* __restrict__ Cb2, int ldcb2)
{
    constexpr int WM = BM / 2, WN = BN / 2, TM = WM / 16, TN = WN / 16;
    static_assert(MODE != 3 || TN == 4, "MODE 3 needs BN=128 (gate quad per thread)");
    __shared__ __attribute__((aligned(16))) short As[TEAMS * 2 * BM * 64];
    __shared__ __attribute__((aligned(16))) short Bs[TEAMS * 2 * BN * 64];

    const int t    = threadIdx.x;
    const int tk   = t >> 8;          // K-team
    const int lt   = t & 255;
    const int lane = lt & 63;
    const int w    = lt >> 6;
    const int wm   = w >> 1, wn = w & 1;
    const int m0   = blockIdx.y * BM;
    const int n0   = blockIdx.x * BN;
    const int kb   = tk * (K / TEAMS);

    const int r8 = lane >> 3;
    const int cx = (lane & 7) ^ r8;   // chunk c stored at in-row slot c^row
    const int q  = lane >> 4;
    const int ml = lane & 15;

    short* Ast = As + tk * (2 * BM * 64);   // team LDS regions
    short* Bst = Bs + tk * (2 * BN * 64);

    floatx4 acc[TM][TN];
    const floatx4 zf = {0.f, 0.f, 0.f, 0.f};
    #pragma unroll
    for (int i = 0; i < TM; ++i)
        #pragma unroll
        for (int j = 0; j < TN; ++j) acc[i][j] = zf;

    auto stage = [&](int k0, int buf) {
        short* ad = Ast + buf * (BM * 64);
        short* bd = Bst + buf * (BN * 64);
        #pragma unroll
        for (int u = 0; u < BM / 32; ++u) {
            const int row = w * (BM / 4) + u * 8;
            async16(A + (size_t)(m0 + row + r8) * lda + k0 + cx * 8, ad + row * 64);
        }
        #pragma unroll
        for (int u = 0; u < BN / 32; ++u) {
            const int row = w * (BN / 4) + u * 8;
            async16(W + (size_t)(n0 + row + r8) * ldw + k0 + cx * 8, bd + row * 64);
        }
    };

    stage(kb, 0);
    __syncthreads();                                     // drains vmcnt -> buf0 ready
    const int nk = (K / TEAMS) / 64;
    for (int it = 0; it < nk; ++it) {
        if (it + 1 < nk) stage(kb + (it + 1) * 64, (it + 1) & 1);   // prefetch next
        const short* as = Ast + (it & 1) * (BM * 64);
        const short* bs = Bst + (it & 1) * (BN * 64);
        #pragma unroll
        for (int s = 0; s < 2; ++s) {
            short8 af[TM], bfr[TN];
            #pragma unroll
            for (int i = 0; i < TM; ++i) {
                const int m = wm * WM + i * 16 + ml;
                af[i] = *(const short8*)&as[(m * 8 + ((s * 4 + q) ^ (m & 7))) * 8];
            }
            #pragma unroll
            for (int j = 0; j < TN; ++j) {
                const int n = wn * WN + j * 16 + ml;
                bfr[j] = *(const short8*)&bs[(n * 8 + ((s * 4 + q) ^ (n & 7))) * 8];
            }
            #pragma unroll
            for (int i = 0; i < TM; ++i)
                #pragma unroll
                for (int j = 0; j < TN; ++j)
                    acc[i][j] = __builtin_amdgcn_mfma_f32_16x16x32_bf16(af[i], bfr[j], acc[i][j], 0, 0, 0);
        }
        __syncthreads();                                 // drain prefetch + protect bufs
    }

    // cross-team reduction: teams >=1 write acc into their OWN dead B region
    // (2*BN*64*2B >= 256*TM*TN*16B for all instantiations), thread-flat.
    if (tk > 0) {
        floatx4* ex = (floatx4*)(Bs + (size_t)tk * (2 * BN * 64));
        #pragma unroll
        for (int i = 0; i < TM; ++i)
            #pragma unroll
            for (int j = 0; j < TN; ++j)
                ex[lt * (TM * TN) + i * TN + j] = acc[i][j];
    }
    __syncthreads();
    if (tk != 0) return;
    #pragma unroll
    for (int src = 1; src < TEAMS; ++src) {
        const floatx4* ex = (const floatx4*)(Bs + (size_t)src * (2 * BN * 64));
        #pragma unroll
        for (int i = 0; i < TM; ++i)
            #pragma unroll
            for (int j = 0; j < TN; ++j) {
                const floatx4 o = ex[lt * (TM * TN) + i * TN + j];
                acc[i][j][0] += o[0]; acc[i][j][1] += o[1];
                acc[i][j][2] += o[2]; acc[i][j][3] += o[3];
            }
    }

    // epilogue (team 0): C/D layout col = lane&15, row = q*4 + reg
    const int gmb = m0 + wm * WM + q * 4;
    if constexpr (MODE == 3) {
        const int nn = n0 + wn * WN;
        const int jj = (nn >> 6) * 16 + ml;
        const float bI = bias[nn + ml],      bF = bias[nn + 16 + ml];
        const float bG = bias[nn + 32 + ml], bO = bias[nn + 48 + ml];
        #pragma unroll
        for (int i = 0; i < TM; ++i)
            #pragma unroll
            for (int r = 0; r < 4; ++r) {
                const int b = gmb + i * 16 + r;
                const float i_ = sigmoid_f(acc[i][0][r] + bI);
                const float f_ = sigmoid_f(acc[i][1][r] + bF);
                const float g_ = tanh_f(acc[i][2][r] + bG);
                const float o_ = sigmoid_f(acc[i][3][r] + bO);
                float* cp = Cf + (size_t)b * ldc + jj;   // unique owner thread
                const float cn = f_ * (*cp) + i_ * g_;
                *cp = cn;
                const unsigned short hb = f2bf(o_ * tanh_f(cn));
                Cb[(size_t)b * ldcb + jj] = hb;
                if (Cb2) Cb2[(size_t)b * ldcb2 + jj] = hb;
            }
    } else {
        const int gnb = n0 + wn * WN + ml;
        #pragma unroll
        for (int i = 0; i < TM; ++i)
            #pragma unroll
            for (int j = 0; j < TN; ++j) {
                const int gm = gmb + i * 16, gn = gnb + j * 16;
                const float bv = bias[gn];
                #pragma unroll
                for (int r = 0; r < 4; ++r) {
                    float v = acc[i][j][r] + bv;
                    if (MODE == 1) v = fmaxf(v, 0.f);
                    if (MODE == 2) Cf[(size_t)(gm + r) * ldc + gn] = v;
                    Cb[(size_t)(gm + r) * ldcb + gn] = f2bf(v);
                }
            }
    }
}

// ---------------------------------------------------------------------------
// Weight packing (verified)
// ---------------------------------------------------------------------------
__global__ __launch_bounds__(256)
void pack_gates(const float* __restrict__ w_ih, int Kih,
                const float* __restrict__ w_hh, int Khh,
                const float* __restrict__ b_ih, const float* __restrict__ b_hh,
                unsigned short* __restrict__ d, float* __restrict__ bc, int K)
{
    const int idx = blockIdx.x * 256 + threadIdx.x;
    if (idx >= 4096 * K) return;
    const int p = idx / K;
    const int k = idx - p * K;
    const int g = (p >> 4) & 3;
    const int j = ((p >> 6) << 4) | (p & 15);
    const int orow = g * 1024 + j;
    const float v = (k < Kih) ? w_ih[(size_t)orow * Kih + k]
                              : w_hh[(size_t)orow * Khh + (k - Kih)];
    d[idx] = f2bf(v);
    if (k == 0) bc[p] = b_ih[orow] + b_hh[orow];
}

__global__ __launch_bounds__(256)
void pack2(const float* __restrict__ s1, int K1, const float* __restrict__ s2, int K2,
           unsigned short* __restrict__ d, int total, int K)
{
    const int idx = blockIdx.x * 256 + threadIdx.x;
    if (idx >= total) return;
    const int n = idx / K;
    const int k = idx - n * K;
    const float v = (k < K1) ? s1[(size_t)n * K1 + k] : s2[(size_t)n * K2 + (k - K1)];
    d[idx] = f2bf(v);
}

// ---------------------------------------------------------------------------
// fp32 prologue GEMM (attention + prior): small, runs once. C2 = bf16 copy.
// ---------------------------------------------------------------------------
template<int RELU>
__global__ __launch_bounds__(256)
void gemm_tn(const float* __restrict__ A1, int lda1,
             const float* __restrict__ W1, int ldw1, int K1,
             const float* __restrict__ A2, int lda2,
             const float* __restrict__ W2, int ldw2, int K2,
             const float* __restrict__ bias1,
             float* __restrict__ C, int ldc,
             unsigned short* __restrict__ C2, int ldc2,
             int M, int N)
{
    __shared__ float As[16][64];
    __shared__ float Ws[16][64];
    const int t   = threadIdx.x;
    const int bn0 = blockIdx.x * 64;
    const int bm0 = blockIdx.y * 64;
    const int tx  = t & 15;
    const int ty  = t >> 4;
    const int lr  = t >> 2;
    const int lc  = (t & 3) << 2;

    float acc[4][4] = {};

    for (int src = 0; src < 2; ++src) {
        const float* A = src ? A2 : A1;
        if (!A) continue;
        const float* W = src ? W2 : W1;
        const int lda = src ? lda2 : lda1;
        const int ldw = src ? ldw2 : ldw1;
        const int K   = src ? K2 : K1;
        for (int k0 = 0; k0 < K; k0 += 16) {
            float4 av = make_float4(0.f, 0.f, 0.f, 0.f);
            const int am = bm0 + lr;
            if (am < M) av = *(const float4*)(A + (size_t)am * lda + k0 + lc);
            const float4 wv = *(const float4*)(W + (size_t)(bn0 + lr) * ldw + k0 + lc);
            __syncthreads();
            As[lc + 0][lr] = av.x; As[lc + 1][lr] = av.y;
            As[lc + 2][lr] = av.z; As[lc + 3][lr] = av.w;
            Ws[lc + 0][lr] = wv.x; Ws[lc + 1][lr] = wv.y;
            Ws[lc + 2][lr] = wv.z; Ws[lc + 3][lr] = wv.w;
            __syncthreads();
            #pragma unroll
            for (int kk = 0; kk < 16; ++kk) {
                const float4 a = *(const float4*)&As[kk][ty * 4];
                const float4 b = *(const float4*)&Ws[kk][tx * 4];
                const float ar[4] = {a.x, a.y, a.z, a.w};
                const float br[4] = {b.x, b.y, b.z, b.w};
                #pragma unroll
                for (int i = 0; i < 4; ++i)
                    #pragma unroll
                    for (int j = 0; j < 4; ++j)
                        acc[i][j] = fmaf(ar[i], br[j], acc[i][j]);
            }
        }
    }

    const int n0 = bn0 + tx * 4;
    float bv[4] = {0.f, 0.f, 0.f, 0.f};
    if (bias1) {
        #pragma unroll
        for (int j = 0; j < 4; ++j) bv[j] += bias1[n0 + j];
    }
    #pragma unroll
    for (int i = 0; i < 4; ++i) {
        const int m = bm0 + ty * 4 + i;
        if (m < M) {
            float ov[4];
            #pragma unroll
            for (int j = 0; j < 4; ++j) {
                float v = acc[i][j] + bv[j];
                if (RELU) v = fmaxf(v, 0.f);
                ov[j] = v;
            }
            *(float4*)(C + (size_t)m * ldc + n0) = make_float4(ov[0], ov[1], ov[2], ov[3]);
            if (C2) {
                #pragma unroll
                for (int j = 0; j < 4; ++j)
                    C2[(size_t)m * ldc2 + n0 + j] = f2bf(ov[j]);
            }
        }
    }
}

__global__ __launch_bounds__(256)
void attn_kernel(const float* __restrict__ q, const float* __restrict__ k,
                 const float* __restrict__ v, float* __restrict__ ctx)
{
    __shared__ float red[NSLOT][4];
    __shared__ float wts[NSLOT];
    const int b = blockIdx.x;
    const int t = threadIdx.x;
    const float4 qv = *(const float4*)(q + (size_t)b * HID + t * 4);
    #pragma unroll
    for (int s = 0; s < NSLOT; ++s) {
        const float4 kv = *(const float4*)(k + (size_t)s * HID + t * 4);
        float p = qv.x * kv.x + qv.y * kv.y + qv.z * kv.z + qv.w * kv.w;
        #pragma unroll
        for (int off = 32; off > 0; off >>= 1) p += __shfl_down(p, off);
        if ((t & 63) == 0) red[s][t >> 6] = p;
    }
    __syncthreads();
    if (t == 0) {
        float sc[NSLOT];
        float mx = -1e30f;
        for (int s = 0; s < NSLOT; ++s) {
            sc[s] = (red[s][0] + red[s][1] + red[s][2] + red[s][3]) * 0.03125f;
            mx = fmaxf(mx, sc[s]);
        }
        float sum = 0.f;
        for (int s = 0; s < NSLOT; ++s) { const float e = __expf(sc[s] - mx); wts[s] = e; sum += e; }
        const float inv = 1.f / sum;
        for (int s = 0; s < NSLOT; ++s) wts[s] *= inv;
    }
    __syncthreads();
    float4 a = make_float4(0.f, 0.f, 0.f, 0.f);
    #pragma unroll
    for (int s = 0; s < NSLOT; ++s) {
        const float wv = wts[s];
        const float4 vv = *(const float4*)(v + (size_t)s * HID + t * 4);
        a.x += wv * vv.x; a.y += wv * vv.y; a.z += wv * vv.z; a.w += wv * vv.w;
    }
    *(float4*)(ctx + (size_t)b * HID + t * 4) = a;
}

extern "C" void kernel_launch(void* const* d_in, const int* in_sizes, int n_in,
                              void* d_out, int out_size, void* d_ws, size_t ws_size,
                              hipStream_t stream)
{
    const float* cs    = (const float*)d_in[0];
    const float* mem   = (const float*)d_in[2];
    const float* q_W   = (const float*)d_in[3];
    const float* q_b   = (const float*)d_in[4];
    const float* k_W   = (const float*)d_in[5];
    const float* k_b   = (const float*)d_in[6];
    const float* v_W   = (const float*)d_in[7];
    const float* v_b   = (const float*)d_in[8];
    const float* mo_W  = (const float*)d_in[9];
    const float* mo_b  = (const float*)d_in[10];
    const float* pg_W1 = (const float*)d_in[11];
    const float* pg_b1 = (const float*)d_in[12];
    const float* pg_W2 = (const float*)d_in[13];
    const float* pg_b2 = (const float*)d_in[14];
    const float* w_ih0 = (const float*)d_in[15];
    const float* w_hh0 = (const float*)d_in[16];
    const float* b_ih0 = (const float*)d_in[17];
    const float* b_hh0 = (const float*)d_in[18];
    const float* w_ih1 = (const float*)d_in[19];
    const float* w_hh1 = (const float*)d_in[20];
    const float* b_ih1 = (const float*)d_in[21];
    const float* b_hh1 = (const float*)d_in[22];
    const float* op_W1 = (const float*)d_in[23];
    const float* op_b1 = (const float*)d_in[24];
    const float* op_W2 = (const float*)d_in[25];
    const float* op_b2 = (const float*)d_in[26];

    float* out       = (float*)d_out;
    float* prior_out = out + (size_t)NB * HOR * LAT;

    char* base = (char*)d_ws;
    auto alloc = [&](size_t bytes) { char* r = base; base += (bytes + 255) & ~255ull; return r; };

    unsigned short* Wg0p = (unsigned short*)alloc((size_t)4 * HID * (LAT + HID) * 2);
    unsigned short* Wg1p = (unsigned short*)alloc((size_t)4 * HID * (2 * HID) * 2);
    unsigned short* Wo1  = (unsigned short*)alloc((size_t)HID * HID * 2);
    unsigned short* Wo2  = (unsigned short*)alloc((size_t)LAT * HID * 2);
    float*          bc0  = (float*)alloc((size_t)4 * HID * 4);
    float*          bc1  = (float*)alloc((size_t)4 * HID * 4);
    // zero-init region (contiguous, 256B-multiple sizes): xh0[2], hh1[2], c0, c1
    unsigned short* xh0  = (unsigned short*)alloc((size_t)2 * NB * (LAT + HID) * 2);
    unsigned short* hh1  = (unsigned short*)alloc((size_t)2 * NB * (2 * HID) * 2);
    float*          c0   = (float*)alloc((size_t)NB * HID * 4);
    float*          c1   = (float*)alloc((size_t)NB * HID * 4);
    unsigned short* tbuf = (unsigned short*)alloc((size_t)NB * HID * 2);
    float* qbuf   = (float*)alloc((size_t)NB * HID * 4);
    float* kbuf   = (float*)alloc((size_t)NSLOT * HID * 4);
    float* vbuf   = (float*)alloc((size_t)NSLOT * HID * 4);
    float* ctxbuf = (float*)alloc((size_t)NB * HID * 4);
    float* ctxo   = (float*)alloc((size_t)NB * LAT * 4);
    float* pgh    = (float*)alloc((size_t)NB * HID * 4);

    const size_t zbytes = (size_t)2 * NB * (LAT + HID) * 2
                        + (size_t)2 * NB * (2 * HID) * 2
                        + (size_t)NB * HID * 4 * 2;
    hipMemsetAsync(xh0, 0, zbytes, stream);

    const dim3 blk(256);
    const dim3 blk1k(1024);

    // ---- pack weights (gates: gate-interleaved + combined bias) ----
    {
        int tot = 4 * HID * (LAT + HID);
        pack_gates<<<dim3((tot + 255) / 256), blk, 0, stream>>>(
            w_ih0, LAT, w_hh0, HID, b_ih0, b_hh0, Wg0p, bc0, LAT + HID);
        tot = 4 * HID * (2 * HID);
        pack_gates<<<dim3((tot + 255) / 256), blk, 0, stream>>>(
            w_ih1, HID, w_hh1, HID, b_ih1, b_hh1, Wg1p, bc1, 2 * HID);
        tot = HID * HID;
        pack2<<<dim3((tot + 255) / 256), blk, 0, stream>>>(op_W1, HID, nullptr, 0, Wo1, tot, HID);
        tot = LAT * HID;
        pack2<<<dim3((tot + 255) / 256), blk, 0, stream>>>(op_W2, HID, nullptr, 0, Wo2, tot, HID);
    }

    // ---- prologue (fp32): attention read + prior ----
    gemm_tn<0><<<dim3(HID / 64, 1), blk, 0, stream>>>(
        mem, HID, k_W, HID, HID, nullptr, 0, nullptr, 0, 0,
        k_b, kbuf, HID, nullptr, 0, NSLOT, HID);
    gemm_tn<0><<<dim3(HID / 64, 1), blk, 0, stream>>>(
        mem, HID, v_W, HID, HID, nullptr, 0, nullptr, 0, 0,
        v_b, vbuf, HID, nullptr, 0, NSLOT, HID);
    gemm_tn<0><<<dim3(HID / 64, NB / 64), blk, 0, stream>>>(
        cs, LAT, q_W, LAT, LAT, nullptr, 0, nullptr, 0, 0,
        q_b, qbuf, HID, nullptr, 0, NB, HID);
    attn_kernel<<<dim3(NB), blk, 0, stream>>>(qbuf, kbuf, vbuf, ctxbuf);
    gemm_tn<0><<<dim3(LAT / 64, NB / 64), blk, 0, stream>>>(
        ctxbuf, HID, mo_W, HID, HID, nullptr, 0, nullptr, 0, 0,
        mo_b, ctxo, LAT, nullptr, 0, NB, LAT);
    gemm_tn<1><<<dim3(HID / 64, NB / 64), blk, 0, stream>>>(
        cs, LAT, pg_W1, HID, LAT, ctxo, LAT, pg_W1 + LAT, HID, LAT,
        pg_b1, pgh, HID, nullptr, 0, NB, HID);
    // prior -> fp32 output AND bf16 x0 into xh0 buffer 0 (first 512 cols)
    gemm_tn<0><<<dim3(LAT / 64, NB / 64), blk, 0, stream>>>(
        pgh, HID, pg_W2, HID, HID, nullptr, 0, nullptr, 0, 0,
        pg_b2, prior_out, LAT, xh0, LAT + HID, NB, LAT);

    // ---- LSTM rollout: 4 dispatches/step, pw fused, 4 K-teams per block ----
    for (int step = 0; step < HOR; ++step) {
        const int cur = step & 1, nxt = cur ^ 1;
        unsigned short* xh_r = xh0 + (size_t)cur * NB * (LAT + HID);
        unsigned short* xh_w = xh0 + (size_t)nxt * NB * (LAT + HID);
        unsigned short* hh_c = hh1 + (size_t)cur * NB * (2 * HID);
        unsigned short* hh_n = hh1 + (size_t)nxt * NB * (2 * HID);

        // gates0 + pw: h0 -> hh_c[:, :HID] (this step) AND xh_w[:, LAT:] (next)
        mfma_gemm<32, 128, 3, 4><<<dim3(4 * HID / 128, NB / 32), blk1k, 0, stream>>>(
            xh_r, LAT + HID, Wg0p, LAT + HID, LAT + HID,
            bc0, c0, HID, hh_c, 2 * HID, xh_w + LAT, LAT + HID);
        // gates1 + pw: h1 -> hh_n[:, HID:]
        mfma_gemm<32, 128, 3, 4><<<dim3(4 * HID / 128, NB / 32), blk1k, 0, stream>>>(
            hh_c, 2 * HID, Wg1p, 2 * HID, 2 * HID,
            bc1, c1, HID, hh_n + HID, 2 * HID, nullptr, 0);
        // op1: t = relu(h1 @ Wo1^T + b1) -> tbuf (bf16)
        mfma_gemm<64, 64, 1, 4><<<dim3(HID / 64, NB / 64), blk1k, 0, stream>>>(
            hh_n + HID, 2 * HID, Wo1, HID, HID,
            op_b1, nullptr, 0, tbuf, HID, nullptr, 0);
        // op2: pred = t @ Wo2^T + b2 -> out[:,step,:] fp32 AND xh_w[:, :LAT] bf16
        mfma_gemm<64, 64, 2, 4><<<dim3(LAT / 64, NB / 64), blk1k, 0, stream>>>(
            tbuf, HID, Wo2, HID, HID,
            op_b2, out + (size_t)step * LAT, HOR * LAT, xh_w, LAT + HID, nullptr, 0);
    }
}